// Round 3
// baseline (26.532 us; speedup 1.0000x reference)
//
#include <hip/hip_runtime.h>

// GaussianCategoricalSampler:
//   pattern [1,4,8,16] x16 -> 64 output cols, 480 input cols per row.
//   size<=1: consumes 2 cols, emits col0 (mu).
//   size>1 : consumes size cols, emits argmax (softmax->clip->renorm is
//            weakly monotone => argmax of raw logits, first-max tie-break).
//
// Structure: per-WAVE independent tiles, no __syncthreads.
//   wave = 4 rows; stages 1920 floats via global_load_lds (7x16B + 2x4B),
//   waits vmcnt(0), then lane (r,h) = 4 outputs from 30 consecutive floats.
//   LDS 30 KB/block -> 5 blocks/CU = 20 waves/CU.

constexpr int WIDTH   = 480;
constexpr int NOUT    = 64;
constexpr int WAVES   = 4;    // per block
constexpr int RPW     = 4;    // rows per wave
constexpr int RPB     = WAVES * RPW;   // 16 rows per block
constexpr int THREADS = WAVES * 64;

__device__ __forceinline__ void async_cp16(const float* g, float* l) {
    __builtin_amdgcn_global_load_lds(
        (const __attribute__((address_space(1))) void*)g,
        (__attribute__((address_space(3))) void*)l, 16, 0, 0);
}
__device__ __forceinline__ void async_cp4(const float* g, float* l) {
    __builtin_amdgcn_global_load_lds(
        (const __attribute__((address_space(1))) void*)g,
        (__attribute__((address_space(3))) void*)l, 4, 0, 0);
}

template <int N>
__device__ __forceinline__ float argmaxN(const float* __restrict__ p) {
    float best = p[0];
    int   bi   = 0;
#pragma unroll
    for (int i = 1; i < N; ++i) {
        if (p[i] > best) { best = p[i]; bi = i; }  // strict > == jnp first-max
    }
    return (float)bi;
}

__global__ __launch_bounds__(THREADS)
void gcs_kernel(const float* __restrict__ in, float* __restrict__ out) {
    __shared__ float lds[WAVES * RPW * WIDTH];   // 7680 floats = 30 KB

    const int wid  = threadIdx.x >> 6;
    const int lane = threadIdx.x & 63;

    const size_t tile_row0 = (size_t)blockIdx.x * RPB + wid * RPW;
    const float* gsrc  = in + tile_row0 * WIDTH;          // 1920 floats, contiguous
    float*       lbase = &lds[wid * RPW * WIDTH];

    // ---- Stage 1920 floats: 7 x (64 lanes x 16B) + 2 x (64 lanes x 4B).
    //      LDS dest is linear (HW: wave-uniform base + lane*size).
#pragma unroll
    for (int k = 0; k < 7; ++k)
        async_cp16(gsrc + k * 256 + lane * 4, lbase + k * 256 + lane * 4);
    async_cp4(gsrc + 1792 + lane, lbase + 1792 + lane);
    async_cp4(gsrc + 1856 + lane, lbase + 1856 + lane);

    // Wave-local completion wait: each wave reads only LDS it staged itself.
    asm volatile("s_waitcnt vmcnt(0)" ::: "memory");

    // ---- Compute: lane = (row-in-wave r, half-octet h). 30 floats -> 4 outs.
    const int r = lane >> 4;     // 0..3
    const int h = lane & 15;     // 0..15
    const float2* w2 = reinterpret_cast<const float2*>(lbase + r * WIDTH + h * 30);

    float v[30];
#pragma unroll
    for (int i = 0; i < 15; ++i) {
        float2 t = w2[i];
        v[2 * i]     = t.x;
        v[2 * i + 1] = t.y;
    }

    float4 o;
    o.x = v[0];                  // mu      (cols 0..1)
    o.y = argmaxN<4>(v + 2);     // size 4  (cols 2..5)
    o.z = argmaxN<8>(v + 6);     // size 8  (cols 6..13)
    o.w = argmaxN<16>(v + 14);   // size 16 (cols 14..29)

    // ---- Coalesced store: wave writes 1 KB contiguous.
    *reinterpret_cast<float4*>(out + (tile_row0 + r) * NOUT + h * 4) = o;
}

extern "C" void kernel_launch(void* const* d_in, const int* in_sizes, int n_in,
                              void* d_out, int out_size, void* d_ws, size_t ws_size,
                              hipStream_t stream) {
    const float* in  = (const float*)d_in[0];
    float*       out = (float*)d_out;

    int batch  = in_sizes[0] / WIDTH;   // 65536
    int blocks = batch / RPB;           // 4096

    gcs_kernel<<<blocks, THREADS, 0, stream>>>(in, out);
}

// Round 4
// 25.806 us; speedup vs baseline: 1.0281x; 1.0281x over previous
//
#include <hip/hip_runtime.h>

// GaussianCategoricalSampler:
//   pattern [1,4,8,16] x16 -> 64 output cols, 480 input cols per row.
//   size<=1: consumes 2 cols, emits col0 (mu).
//   size>1 : consumes size cols, emits argmax (softmax->clip->renorm is
//            weakly monotone => argmax of raw logits, first-max tie-break).
//
// R3: persistent waves, double-buffered LDS, vmcnt-COUNTED cross-tile
//     pipeline (T3/T4 pattern). Wave owns 16 consecutive rows = 4 tiles of
//     4 rows; stage(t+1) issues before compute(t); wait vmcnt(9) keeps the
//     next tile's 9 loads in flight under the compute phase. Only one full
//     drain per wave (was one per 4-row tile).

constexpr int WIDTH   = 480;
constexpr int NOUT    = 64;
constexpr int RPW     = 4;     // rows per tile per wave
constexpr int TPW     = 4;     // tiles per wave
constexpr int WAVES   = 4;     // waves per block
constexpr int THREADS = WAVES * 64;
constexpr int TILE_F  = RPW * WIDTH;   // 1920 floats per tile buffer

__device__ __forceinline__ void async_cp16(const float* g, float* l) {
    __builtin_amdgcn_global_load_lds(
        (const __attribute__((address_space(1))) void*)g,
        (__attribute__((address_space(3))) void*)l, 16, 0, 0);
}
__device__ __forceinline__ void async_cp4(const float* g, float* l) {
    __builtin_amdgcn_global_load_lds(
        (const __attribute__((address_space(1))) void*)g,
        (__attribute__((address_space(3))) void*)l, 4, 0, 0);
}

// Stage one 1920-float tile: 7 x (64 lanes x 16B) + 2 x (64 lanes x 4B) = 9 VMEM.
__device__ __forceinline__ void stage_tile(const float* g, float* l, int lane) {
#pragma unroll
    for (int k = 0; k < 7; ++k)
        async_cp16(g + k * 256 + lane * 4, l + k * 256 + lane * 4);
    async_cp4(g + 1792 + lane, l + 1792 + lane);
    async_cp4(g + 1856 + lane, l + 1856 + lane);
}

template <int N>
__device__ __forceinline__ float argmaxN(const float* __restrict__ p) {
    float best = p[0];
    int   bi   = 0;
#pragma unroll
    for (int i = 1; i < N; ++i) {
        if (p[i] > best) { best = p[i]; bi = i; }  // strict > == jnp first-max
    }
    return (float)bi;
}

__device__ __forceinline__ void compute_store(const float* lbase, float* out,
                                              size_t row_base, int lane) {
    const int r = lane >> 4;     // 0..3 row in tile
    const int h = lane & 15;     // 0..15 half-octet
    const float2* w2 = reinterpret_cast<const float2*>(lbase + r * WIDTH + h * 30);

    float v[30];
#pragma unroll
    for (int i = 0; i < 15; ++i) {
        float2 t = w2[i];
        v[2 * i]     = t.x;
        v[2 * i + 1] = t.y;
    }

    float4 o;
    o.x = v[0];                  // mu      (cols 0..1)
    o.y = argmaxN<4>(v + 2);     // size 4  (cols 2..5)
    o.z = argmaxN<8>(v + 6);     // size 8  (cols 6..13)
    o.w = argmaxN<16>(v + 14);   // size 16 (cols 14..29)

    *reinterpret_cast<float4*>(out + (row_base + r) * NOUT + h * 4) = o;
}

__global__ __launch_bounds__(THREADS)
void gcs_kernel(const float* __restrict__ in, float* __restrict__ out) {
    __shared__ float lds[WAVES * 2 * TILE_F];   // 61440 B

    const int wid  = threadIdx.x >> 6;
    const int lane = threadIdx.x & 63;

    const size_t gw   = (size_t)blockIdx.x * WAVES + wid;  // global wave id
    const size_t row0 = gw * (RPW * TPW);                  // 16 rows per wave
    const float* gsrc = in + row0 * WIDTH;

    float* buf0 = &lds[wid * 2 * TILE_F];
    float* buf1 = buf0 + TILE_F;

    // Prologue: stage tile 0.
    stage_tile(gsrc, buf0, lane);

#pragma unroll
    for (int t = 0; t < TPW; ++t) {
        float* cur = (t & 1) ? buf1 : buf0;
        float* nxt = (t & 1) ? buf0 : buf1;
        if (t + 1 < TPW) {
            stage_tile(gsrc + (t + 1) * TILE_F, nxt, lane);
            // cur tile's 9 loads are the oldest; leave the newest 9 in flight.
            asm volatile("s_waitcnt vmcnt(9)" ::: "memory");
        } else {
            // last tile: drain its loads (one prior store may remain).
            asm volatile("s_waitcnt vmcnt(1)" ::: "memory");
        }
        compute_store(cur, out, row0 + (size_t)t * RPW, lane);
    }
}

extern "C" void kernel_launch(void* const* d_in, const int* in_sizes, int n_in,
                              void* d_out, int out_size, void* d_ws, size_t ws_size,
                              hipStream_t stream) {
    const float* in  = (const float*)d_in[0];
    float*       out = (float*)d_out;

    int batch  = in_sizes[0] / WIDTH;            // 65536
    int blocks = batch / (RPW * TPW * WAVES);    // 1024

    gcs_kernel<<<blocks, THREADS, 0, stream>>>(in, out);
}